// Round 1
// baseline (1922.863 us; speedup 1.0000x reference)
//
#include <hip/hip_runtime.h>

// Problem constants (fixed by setup_inputs)
#define N0V 1000000
#define N1V 400000
#define N2V 100000
#define E0V 2000000
#define E1V 500000
#define DD  128
#define HH  50

// Workspace layout (byte offsets)
#define OFF_AGG   0ULL                 // N1*HH f32 = 80,000,000
#define OFF_CNT1  80000000ULL          // N1 f32   =  1,600,000
#define OFF_SSUM  81600000ULL          // N2 f32   =    400,000
#define OFF_CNT2  82000000ULL          // N2 f32   =    400,000
#define ZERO_BYTES 82400000ULL
#define OFF_W     82400000ULL          // wA[50], wB[50], c  (512 B slot)
#define OFF_S     82400512ULL          // N1 f32   =  1,600,000
#define OFF_T     84000512ULL          // N2 f32   =    400,000
#define OFF_Y     84400512ULL          // N0*HH f32 = 200,000,000
#define WS_NEEDED (OFF_Y + 200000000ULL)

// K0: fold layer-2 weights through Wo:  wA = Wl2@Wo, wB = Wr2@Wo, c = bl2.Wo + bo
__global__ void prep_w(const float* __restrict__ Wl2, const float* __restrict__ Wr2,
                       const float* __restrict__ Wo,  const float* __restrict__ bl2,
                       const float* __restrict__ bo,  float* __restrict__ wAB)
{
    int f = threadIdx.x;
    if (f < HH) {
        float a = 0.f, b = 0.f;
        for (int g = 0; g < HH; ++g) {
            float w = Wo[g];
            a += Wl2[f * HH + g] * w;
            b += Wr2[f * HH + g] * w;
        }
        wAB[f] = a;
        wAB[HH + f] = b;
    }
    if (f == 0) {
        float c = bo[0];
        for (int g = 0; g < HH; ++g) c += bl2[g] * Wo[g];
        wAB[2 * HH] = c;
    }
}

// K2: y = x @ Wl1   ([N0,128] @ [128,50]); one thread per node, acc[50] in VGPRs,
// W rows come in as wave-uniform s_loads.
__global__ __launch_bounds__(256) void gemm_y(const float* __restrict__ X,
                                              const float* __restrict__ W,
                                              float* __restrict__ Y)
{
    int i = blockIdx.x * 256 + threadIdx.x;
    if (i >= N0V) return;
    const float4* __restrict__ x4 = (const float4*)(X + (size_t)i * DD);
    float acc[HH];
#pragma unroll
    for (int f = 0; f < HH; ++f) acc[f] = 0.f;
    for (int kt = 0; kt < DD / 4; ++kt) {
        float4 xv = x4[kt];
        float xarr[4] = {xv.x, xv.y, xv.z, xv.w};
#pragma unroll
        for (int j = 0; j < 4; ++j) {
            const float* __restrict__ wrow = W + (size_t)(kt * 4 + j) * HH;
            float xs = xarr[j];
#pragma unroll
            for (int f = 0; f < HH; ++f) acc[f] = fmaf(xs, wrow[f], acc[f]);
        }
    }
    float2* y2 = (float2*)(Y + (size_t)i * HH);
#pragma unroll
    for (int f = 0; f < HH / 2; ++f) y2[f] = make_float2(acc[2 * f], acc[2 * f + 1]);
}

// K3: edge scatter layer 1: agg[dst] += y[src] (50 floats), cnt[dst] += 1
// one thread per (edge, feature)
__global__ __launch_bounds__(256) void scatter1(const float* __restrict__ Y,
                                                const int* __restrict__ src,
                                                const int* __restrict__ dst,
                                                float* __restrict__ agg,
                                                float* __restrict__ cnt)
{
    int t = blockIdx.x * 256 + threadIdx.x;
    if (t >= E0V * HH) return;
    int e = t / HH;
    int f = t - e * HH;
    int sI = src[e];
    int dI = dst[e];
    atomicAdd(&agg[(size_t)dI * HH + f], Y[(size_t)sI * HH + f]);
    if (f == 0) atomicAdd(&cnt[dI], 1.0f);
}

// K4: per-node layer-1 epilogue fused with layer-2 projections:
//   d   = x[i] @ Wr1
//   h   = relu(agg[i]/max(cnt,1) + bl1 + d)     (kept in registers only)
//   s[i] = h . wA ;  t[i] = h . wB (i < N2)
__global__ __launch_bounds__(256) void node_l1(const float* __restrict__ X,
                                               const float* __restrict__ Wr1,
                                               const float* __restrict__ bl1,
                                               const float* __restrict__ agg,
                                               const float* __restrict__ cnt,
                                               const float* __restrict__ wAB,
                                               float* __restrict__ sArr,
                                               float* __restrict__ tArr)
{
    int i = blockIdx.x * 256 + threadIdx.x;
    if (i >= N1V) return;
    const float4* __restrict__ x4 = (const float4*)(X + (size_t)i * DD);
    float acc[HH];
#pragma unroll
    for (int f = 0; f < HH; ++f) acc[f] = 0.f;
    for (int kt = 0; kt < DD / 4; ++kt) {
        float4 xv = x4[kt];
        float xarr[4] = {xv.x, xv.y, xv.z, xv.w};
#pragma unroll
        for (int j = 0; j < 4; ++j) {
            const float* __restrict__ wrow = Wr1 + (size_t)(kt * 4 + j) * HH;
            float xs = xarr[j];
#pragma unroll
            for (int f = 0; f < HH; ++f) acc[f] = fmaf(xs, wrow[f], acc[f]);
        }
    }
    float inv = 1.0f / fmaxf(cnt[i], 1.0f);
    const float2* a2 = (const float2*)(agg + (size_t)i * HH);
    float s_acc = 0.f, t_acc = 0.f;
#pragma unroll
    for (int f = 0; f < HH; f += 2) {
        float2 av = a2[f / 2];
        float h0 = fmaxf(fmaf(av.x, inv, bl1[f] + acc[f]), 0.f);
        float h1 = fmaxf(fmaf(av.y, inv, bl1[f + 1] + acc[f + 1]), 0.f);
        s_acc += h0 * wAB[f] + h1 * wAB[f + 1];
        t_acc += h0 * wAB[HH + f] + h1 * wAB[HH + f + 1];
    }
    sArr[i] = s_acc;
    if (i < N2V) tArr[i] = t_acc;
}

// K5: edge scatter layer 2 (scalar): ssum[dst] += s[src], cnt2[dst] += 1
__global__ __launch_bounds__(256) void scatter2(const float* __restrict__ sArr,
                                                const int* __restrict__ src,
                                                const int* __restrict__ dst,
                                                float* __restrict__ ssum,
                                                float* __restrict__ cnt2)
{
    int e = blockIdx.x * 256 + threadIdx.x;
    if (e >= E1V) return;
    int sI = src[e];
    int dI = dst[e];
    atomicAdd(&ssum[dI], sArr[sI]);
    atomicAdd(&cnt2[dI], 1.0f);
}

// K6: out[i] = relu(ssum[i]/max(cnt2,1) + t[i] + c)
__global__ __launch_bounds__(256) void final_out(const float* __restrict__ ssum,
                                                 const float* __restrict__ cnt2,
                                                 const float* __restrict__ tArr,
                                                 const float* __restrict__ wAB,
                                                 float* __restrict__ out)
{
    int i = blockIdx.x * 256 + threadIdx.x;
    if (i >= N2V) return;
    float c = wAB[2 * HH];
    float inv = 1.0f / fmaxf(cnt2[i], 1.0f);
    float o = fmaf(ssum[i], inv, tArr[i] + c);
    out[i] = fmaxf(o, 0.f);
}

extern "C" void kernel_launch(void* const* d_in, const int* in_sizes, int n_in,
                              void* d_out, int out_size, void* d_ws, size_t ws_size,
                              hipStream_t stream)
{
    if (ws_size < WS_NEEDED) return;  // insufficient scratch -> visible failure

    const float* x    = (const float*)d_in[0];
    const int*   src0 = (const int*)d_in[2];
    const int*   dst0 = (const int*)d_in[3];
    const int*   src1 = (const int*)d_in[4];
    const int*   dst1 = (const int*)d_in[5];
    const float* Wl1  = (const float*)d_in[8];
    const float* bl1  = (const float*)d_in[9];
    const float* Wr1  = (const float*)d_in[10];
    const float* Wl2  = (const float*)d_in[11];
    const float* bl2  = (const float*)d_in[12];
    const float* Wr2  = (const float*)d_in[13];
    const float* Wo   = (const float*)d_in[14];
    const float* bo   = (const float*)d_in[15];
    float* out = (float*)d_out;

    char* ws = (char*)d_ws;
    float* agg  = (float*)(ws + OFF_AGG);
    float* cnt1 = (float*)(ws + OFF_CNT1);
    float* ssum = (float*)(ws + OFF_SSUM);
    float* cnt2 = (float*)(ws + OFF_CNT2);
    float* wAB  = (float*)(ws + OFF_W);
    float* sArr = (float*)(ws + OFF_S);
    float* tArr = (float*)(ws + OFF_T);
    float* y    = (float*)(ws + OFF_Y);

    // zero the accumulators
    hipMemsetAsync(d_ws, 0, ZERO_BYTES, stream);

    prep_w<<<1, 64, 0, stream>>>(Wl2, Wr2, Wo, bl2, bo, wAB);

    gemm_y<<<(N0V + 255) / 256, 256, 0, stream>>>(x, Wl1, y);

    scatter1<<<(E0V * HH + 255) / 256, 256, 0, stream>>>(y, src0, dst0, agg, cnt1);

    node_l1<<<(N1V + 255) / 256, 256, 0, stream>>>(x, Wr1, bl1, agg, cnt1, wAB, sArr, tArr);

    scatter2<<<(E1V + 255) / 256, 256, 0, stream>>>(sArr, src1, dst1, ssum, cnt2);

    final_out<<<(N2V + 255) / 256, 256, 0, stream>>>(ssum, cnt2, tArr, wAB, out);
}

// Round 2
// 1793.331 us; speedup vs baseline: 1.0722x; 1.0722x over previous
//
#include <hip/hip_runtime.h>

// Problem constants (fixed by setup_inputs)
#define N0V 1000000
#define N1V 400000
#define N2V 100000
#define E0V 2000000
#define E1V 500000
#define DD  128
#define HH  50
#define FP  64    // padded feature dim
#define KC  32    // k-chunk staged in LDS

// Workspace layout (byte offsets, all 16B-aligned)
#define OFF_AGG    0ULL                 // N1*HH f32 = 80,000,000
#define OFF_CNT1   80000000ULL          // N1 f32   =  1,600,000
#define OFF_SSUM   81600000ULL          // N2 f32   =    400,000
#define OFF_CNT2   82000000ULL          // N2 f32   =    400,000
#define ZERO_BYTES 82400000ULL
#define OFF_S      82400000ULL          // N1 f32 (fully overwritten)
#define OFF_T      84000000ULL          // N2 f32 (fully overwritten)
#define OFF_Y      84400000ULL          // N0*HH f32 = 200,000,000
#define OFF_WL1P   284400000ULL         // 128*64 f32 = 32,768 B
#define OFF_WR1P   284432768ULL         // 128*64 f32 = 32,768 B
#define OFF_SMALL  284465536ULL         // bl1p[64], wAp[64], wBp[64], c : 1024 B
#define WS_NEEDED  284466560ULL

// K0: pad Wl1/Wr1 to [128][64] (zeros), build bl1p/wAp/wBp (padded) and c.
__global__ void pad_w(const float* __restrict__ Wl1, const float* __restrict__ Wr1,
                      const float* __restrict__ bl1,
                      const float* __restrict__ Wl2, const float* __restrict__ bl2,
                      const float* __restrict__ Wr2, const float* __restrict__ Wo,
                      const float* __restrict__ bo,
                      float* __restrict__ Wl1p, float* __restrict__ Wr1p,
                      float* __restrict__ smalls)
{
    int gid = blockIdx.x * 256 + threadIdx.x;   // 32 blocks -> 8192 threads
    if (gid < 128 * FP) {
        int k = gid >> 6, f = gid & 63;
        float a = (f < HH) ? Wl1[k * HH + f] : 0.f;
        float b = (f < HH) ? Wr1[k * HH + f] : 0.f;
        Wl1p[gid] = a;
        Wr1p[gid] = b;
    }
    if (gid < FP) {
        float a = 0.f, b = 0.f;
        if (gid < HH) {
            for (int g = 0; g < HH; ++g) {
                float w = Wo[g];
                a += Wl2[gid * HH + g] * w;
                b += Wr2[gid * HH + g] * w;
            }
        }
        smalls[gid]          = (gid < HH) ? bl1[gid] : 0.f;  // bl1p
        smalls[FP + gid]     = a;                             // wAp
        smalls[2 * FP + gid] = b;                             // wBp
    }
    if (gid == 0) {
        float c = bo[0];
        for (int g = 0; g < HH; ++g) c += bl2[g] * Wo[g];
        smalls[3 * FP] = c;
    }
}

// K1: y = x @ Wl1p  ([N0,128]@[128,64->50]).
// Block: 256 threads = 32 node-groups x 8 feature-groups; thread tile 8x8.
// x staged via LDS transposed [k][n] with XOR swizzle (write 2-way, read free).
__global__ __launch_bounds__(256, 4) void gemm_y(const float* __restrict__ X,
                                                 const float* __restrict__ Wp,
                                                 float* __restrict__ Y)
{
    __shared__ float xs[KC * 256];   // 32 KB
    const int t  = threadIdx.x;
    const int n0 = blockIdx.x * 256;
    const int ng = t >> 3;           // 0..31
    const int fg = t & 7;            // 0..7
    const int nbase = n0 + ng * 8;

    float acc[8][8];
#pragma unroll
    for (int i = 0; i < 8; ++i)
#pragma unroll
        for (int j = 0; j < 8; ++j) acc[i][j] = 0.f;

    for (int c = 0; c < DD / KC; ++c) {
        if (c) __syncthreads();
        // stage: 256 rows x 32 floats, coalesced 128B per row
#pragma unroll
        for (int j = 0; j < 8; ++j) {
            int f4  = j * 256 + t;
            int row = f4 >> 3;
            int c4  = f4 & 7;
            int gn  = n0 + row;
            float4 v = make_float4(0.f, 0.f, 0.f, 0.f);
            if (gn < N0V) v = *(const float4*)(X + (size_t)gn * DD + c * KC + c4 * 4);
            int kb  = c4 * 4;
            int rsw = row ^ (c4 << 3);           // swizzle by (k>>2)
            xs[(kb + 0) * 256 + rsw] = v.x;
            xs[(kb + 1) * 256 + rsw] = v.y;
            xs[(kb + 2) * 256 + rsw] = v.z;
            xs[(kb + 3) * 256 + rsw] = v.w;
        }
        __syncthreads();
#pragma unroll 4
        for (int kk = 0; kk < KC; ++kk) {
            int m = kk >> 2;
            const float* xp = &xs[kk * 256 + ((ng ^ m) << 3)];
            float4 x0 = *(const float4*)xp;
            float4 x1 = *(const float4*)(xp + 4);
            const float* wr = Wp + (size_t)(c * KC + kk) * FP + fg * 8;
            float4 w0 = *(const float4*)wr;
            float4 w1 = *(const float4*)(wr + 4);
            float xv[8] = {x0.x, x0.y, x0.z, x0.w, x1.x, x1.y, x1.z, x1.w};
            float wv[8] = {w0.x, w0.y, w0.z, w0.w, w1.x, w1.y, w1.z, w1.w};
#pragma unroll
            for (int i = 0; i < 8; ++i)
#pragma unroll
                for (int j = 0; j < 8; ++j)
                    acc[i][j] = fmaf(xv[i], wv[j], acc[i][j]);
        }
    }

    if (nbase < N0V) {   // N0 % 8 == 0 -> group fully valid
#pragma unroll
        for (int i = 0; i < 8; ++i) {
            float* yr = Y + (size_t)(nbase + i) * HH + fg * 8;
            if (fg < 6) {
                *(float2*)(yr + 0) = make_float2(acc[i][0], acc[i][1]);
                *(float2*)(yr + 2) = make_float2(acc[i][2], acc[i][3]);
                *(float2*)(yr + 4) = make_float2(acc[i][4], acc[i][5]);
                *(float2*)(yr + 6) = make_float2(acc[i][6], acc[i][7]);
            } else if (fg == 6) {
                *(float2*)(yr + 0) = make_float2(acc[i][0], acc[i][1]);
            }
        }
    }
}

// K2: edge scatter layer 1: agg[dst] += y[src] (50 floats), cnt[dst] += 1
__global__ __launch_bounds__(256) void scatter1(const float* __restrict__ Y,
                                                const int* __restrict__ src,
                                                const int* __restrict__ dst,
                                                float* __restrict__ agg,
                                                float* __restrict__ cnt)
{
    long long t = (long long)blockIdx.x * 256 + threadIdx.x;
    if (t >= (long long)E0V * HH) return;
    int e = (int)(t / HH);
    int f = (int)(t - (long long)e * HH);
    int sI = src[e];
    int dI = dst[e];
    atomicAdd(&agg[(size_t)dI * HH + f], Y[(size_t)sI * HH + f]);
    if (f == 0) atomicAdd(&cnt[dI], 1.0f);
}

// K3: d = x[:N1] @ Wr1p (same tiled GEMM), then in-register epilogue:
//   h = relu(agg/cnt + bl1 + d);  s = h.wA;  t = h.wB  (shfl-reduce over 8 fgs)
__global__ __launch_bounds__(256, 4) void node_l1(const float* __restrict__ X,
                                                  const float* __restrict__ Wp,
                                                  const float* __restrict__ agg,
                                                  const float* __restrict__ cnt,
                                                  const float* __restrict__ smalls,
                                                  float* __restrict__ sArr,
                                                  float* __restrict__ tArr)
{
    __shared__ float xs[KC * 256];
    const int t  = threadIdx.x;
    const int n0 = blockIdx.x * 256;
    const int ng = t >> 3;
    const int fg = t & 7;
    const int nbase = n0 + ng * 8;

    float acc[8][8];
#pragma unroll
    for (int i = 0; i < 8; ++i)
#pragma unroll
        for (int j = 0; j < 8; ++j) acc[i][j] = 0.f;

    for (int c = 0; c < DD / KC; ++c) {
        if (c) __syncthreads();
#pragma unroll
        for (int j = 0; j < 8; ++j) {
            int f4  = j * 256 + t;
            int row = f4 >> 3;
            int c4  = f4 & 7;
            int gn  = n0 + row;
            float4 v = make_float4(0.f, 0.f, 0.f, 0.f);
            if (gn < N1V) v = *(const float4*)(X + (size_t)gn * DD + c * KC + c4 * 4);
            int kb  = c4 * 4;
            int rsw = row ^ (c4 << 3);
            xs[(kb + 0) * 256 + rsw] = v.x;
            xs[(kb + 1) * 256 + rsw] = v.y;
            xs[(kb + 2) * 256 + rsw] = v.z;
            xs[(kb + 3) * 256 + rsw] = v.w;
        }
        __syncthreads();
#pragma unroll 4
        for (int kk = 0; kk < KC; ++kk) {
            int m = kk >> 2;
            const float* xp = &xs[kk * 256 + ((ng ^ m) << 3)];
            float4 x0 = *(const float4*)xp;
            float4 x1 = *(const float4*)(xp + 4);
            const float* wr = Wp + (size_t)(c * KC + kk) * FP + fg * 8;
            float4 w0 = *(const float4*)wr;
            float4 w1 = *(const float4*)(wr + 4);
            float xv[8] = {x0.x, x0.y, x0.z, x0.w, x1.x, x1.y, x1.z, x1.w};
            float wv[8] = {w0.x, w0.y, w0.z, w0.w, w1.x, w1.y, w1.z, w1.w};
#pragma unroll
            for (int i = 0; i < 8; ++i)
#pragma unroll
                for (int j = 0; j < 8; ++j)
                    acc[i][j] = fmaf(xv[i], wv[j], acc[i][j]);
        }
    }

    if (nbase >= N1V) return;   // N1 % 8 == 0; no further barriers

    // per-lane constants (padded, no guards needed)
    const float* blp = smalls + fg * 8;
    const float* wAp = smalls + FP + fg * 8;
    const float* wBp = smalls + 2 * FP + fg * 8;
    float bl_r[8], wA_r[8], wB_r[8];
#pragma unroll
    for (int j = 0; j < 8; ++j) { bl_r[j] = blp[j]; wA_r[j] = wAp[j]; wB_r[j] = wBp[j]; }

    float4 c0 = *(const float4*)(cnt + nbase);
    float4 c1 = *(const float4*)(cnt + nbase + 4);
    float cv[8] = {c0.x, c0.y, c0.z, c0.w, c1.x, c1.y, c1.z, c1.w};

    float ps[8], pt[8];
#pragma unroll
    for (int i = 0; i < 8; ++i) {
        int n = nbase + i;
        float inv = 1.0f / fmaxf(cv[i], 1.0f);
        float agf[8] = {0.f, 0.f, 0.f, 0.f, 0.f, 0.f, 0.f, 0.f};
        const float* ar = agg + (size_t)n * HH + fg * 8;
        if (fg < 6) {
#pragma unroll
            for (int jj = 0; jj < 4; ++jj) {
                float2 v = *(const float2*)(ar + 2 * jj);
                agf[2 * jj] = v.x; agf[2 * jj + 1] = v.y;
            }
        } else if (fg == 6) {
            float2 v = *(const float2*)ar;
            agf[0] = v.x; agf[1] = v.y;
        }
        float s_acc = 0.f, t_acc = 0.f;
#pragma unroll
        for (int j = 0; j < 8; ++j) {
            float h = fmaxf(fmaf(agf[j], inv, bl_r[j] + acc[i][j]), 0.f);
            s_acc = fmaf(h, wA_r[j], s_acc);
            t_acc = fmaf(h, wB_r[j], t_acc);
        }
        ps[i] = s_acc; pt[i] = t_acc;
    }
    // reduce across the 8 feature lanes (lanes ng*8 .. ng*8+7)
#pragma unroll
    for (int i = 0; i < 8; ++i) {
#pragma unroll
        for (int m = 1; m < 8; m <<= 1) {
            ps[i] += __shfl_xor(ps[i], m);
            pt[i] += __shfl_xor(pt[i], m);
        }
    }
    if (fg == 0) {
#pragma unroll
        for (int i = 0; i < 8; ++i) sArr[nbase + i] = ps[i];
        if (nbase < N2V) {
#pragma unroll
            for (int i = 0; i < 8; ++i) tArr[nbase + i] = pt[i];
        }
    }
}

// K4: edge scatter layer 2 (scalar)
__global__ __launch_bounds__(256) void scatter2(const float* __restrict__ sArr,
                                                const int* __restrict__ src,
                                                const int* __restrict__ dst,
                                                float* __restrict__ ssum,
                                                float* __restrict__ cnt2)
{
    int e = blockIdx.x * 256 + threadIdx.x;
    if (e >= E1V) return;
    int sI = src[e];
    int dI = dst[e];
    atomicAdd(&ssum[dI], sArr[sI]);
    atomicAdd(&cnt2[dI], 1.0f);
}

// K5: out[i] = relu(ssum[i]/max(cnt2,1) + t[i] + c)
__global__ __launch_bounds__(256) void final_out(const float* __restrict__ ssum,
                                                 const float* __restrict__ cnt2,
                                                 const float* __restrict__ tArr,
                                                 const float* __restrict__ smalls,
                                                 float* __restrict__ out)
{
    int i = blockIdx.x * 256 + threadIdx.x;
    if (i >= N2V) return;
    float c = smalls[3 * FP];
    float inv = 1.0f / fmaxf(cnt2[i], 1.0f);
    float o = fmaf(ssum[i], inv, tArr[i] + c);
    out[i] = fmaxf(o, 0.f);
}

extern "C" void kernel_launch(void* const* d_in, const int* in_sizes, int n_in,
                              void* d_out, int out_size, void* d_ws, size_t ws_size,
                              hipStream_t stream)
{
    if (ws_size < WS_NEEDED) return;

    const float* x    = (const float*)d_in[0];
    const int*   src0 = (const int*)d_in[2];
    const int*   dst0 = (const int*)d_in[3];
    const int*   src1 = (const int*)d_in[4];
    const int*   dst1 = (const int*)d_in[5];
    const float* Wl1  = (const float*)d_in[8];
    const float* bl1  = (const float*)d_in[9];
    const float* Wr1  = (const float*)d_in[10];
    const float* Wl2  = (const float*)d_in[11];
    const float* bl2  = (const float*)d_in[12];
    const float* Wr2  = (const float*)d_in[13];
    const float* Wo   = (const float*)d_in[14];
    const float* bo   = (const float*)d_in[15];
    float* out = (float*)d_out;

    char* ws = (char*)d_ws;
    float* agg    = (float*)(ws + OFF_AGG);
    float* cnt1   = (float*)(ws + OFF_CNT1);
    float* ssum   = (float*)(ws + OFF_SSUM);
    float* cnt2   = (float*)(ws + OFF_CNT2);
    float* sArr   = (float*)(ws + OFF_S);
    float* tArr   = (float*)(ws + OFF_T);
    float* y      = (float*)(ws + OFF_Y);
    float* Wl1p   = (float*)(ws + OFF_WL1P);
    float* Wr1p   = (float*)(ws + OFF_WR1P);
    float* smalls = (float*)(ws + OFF_SMALL);

    hipMemsetAsync(d_ws, 0, ZERO_BYTES, stream);

    pad_w<<<32, 256, 0, stream>>>(Wl1, Wr1, bl1, Wl2, bl2, Wr2, Wo, bo, Wl1p, Wr1p, smalls);

    gemm_y<<<(N0V + 255) / 256, 256, 0, stream>>>(x, Wl1p, y);

    long long s1_threads = (long long)E0V * HH;
    scatter1<<<(unsigned)((s1_threads + 255) / 256), 256, 0, stream>>>(y, src0, dst0, agg, cnt1);

    node_l1<<<(N1V + 255) / 256, 256, 0, stream>>>(x, Wr1p, agg, cnt1, smalls, sArr, tArr);

    scatter2<<<(E1V + 255) / 256, 256, 0, stream>>>(sArr, src1, dst1, ssum, cnt2);

    final_out<<<(N2V + 255) / 256, 256, 0, stream>>>(ssum, cnt2, tArr, smalls, out);
}

// Round 3
// 1545.737 us; speedup vs baseline: 1.2440x; 1.1602x over previous
//
#include <hip/hip_runtime.h>

// Problem constants (fixed by setup_inputs)
#define N0V 1000000
#define N1V 400000
#define N2V 100000
#define E0V 2000000
#define E1V 500000
#define DD  128
#define HH  50
#define FP  64    // padded feature dim
#define KC  32    // k-chunk staged in LDS
#define NB_SCAN 1563   // ceil(N1V/256)

// Workspace layout (byte offsets, all 16B-aligned)
#define OFF_DEG    0ULL                 // N1 int  = 1,600,000
#define OFF_SSUM   1600000ULL           // N2 f32  =   400,000
#define OFF_CNT2   2000000ULL           // N2 f32  =   400,000
#define ZERO_BYTES 2400000ULL
#define OFF_ROWPTR 2400000ULL           // N1 int  = 1,600,000
#define OFF_CURSOR 4000000ULL           // N1 int  = 1,600,000
#define OFF_BSUM   5600000ULL           // NB_SCAN int (pad to 8192 B)
#define OFF_SMALL  5608192ULL           // bl1p[64], wAp[64], wBp[64], c : 1024 B
#define OFF_WL1P   5609216ULL           // 128*64 f32 = 32,768
#define OFF_WR1P   5641984ULL           // 128*64 f32 = 32,768
#define OFF_S      5674752ULL           // N1 f32 = 1,600,000
#define OFF_T      7274752ULL           // N2 f32 =   400,000
#define OFF_CSR    7674752ULL           // E0 int = 8,000,000
#define OFF_AGG    15674752ULL          // N1*FP f32 = 102,400,000 (stores MEAN)
#define OFF_Y      118074752ULL         // N0*FP bf16 = 128,000,000
#define WS_NEEDED  246074752ULL

__device__ inline unsigned short f2bf(float f) {
    unsigned int u = __float_as_uint(f);
    unsigned int r = (u + 0x7FFFu + ((u >> 16) & 1u)) >> 16;
    return (unsigned short)r;
}

// K0: pad Wl1/Wr1 to [128][64] (zeros), build bl1p/wAp/wBp (padded) and c.
__global__ void pad_w(const float* __restrict__ Wl1, const float* __restrict__ Wr1,
                      const float* __restrict__ bl1,
                      const float* __restrict__ Wl2, const float* __restrict__ bl2,
                      const float* __restrict__ Wr2, const float* __restrict__ Wo,
                      const float* __restrict__ bo,
                      float* __restrict__ Wl1p, float* __restrict__ Wr1p,
                      float* __restrict__ smalls)
{
    int gid = blockIdx.x * 256 + threadIdx.x;   // 32 blocks -> 8192 threads
    if (gid < 128 * FP) {
        int k = gid >> 6, f = gid & 63;
        float a = (f < HH) ? Wl1[k * HH + f] : 0.f;
        float b = (f < HH) ? Wr1[k * HH + f] : 0.f;
        Wl1p[gid] = a;
        Wr1p[gid] = b;
    }
    if (gid < FP) {
        float a = 0.f, b = 0.f;
        if (gid < HH) {
            for (int g = 0; g < HH; ++g) {
                float w = Wo[g];
                a += Wl2[gid * HH + g] * w;
                b += Wr2[gid * HH + g] * w;
            }
        }
        smalls[gid]          = (gid < HH) ? bl1[gid] : 0.f;  // bl1p
        smalls[FP + gid]     = a;                             // wAp
        smalls[2 * FP + gid] = b;                             // wBp
    }
    if (gid == 0) {
        float c = bo[0];
        for (int g = 0; g < HH; ++g) c += bl2[g] * Wo[g];
        smalls[3 * FP] = c;
    }
}

// K1: y = x @ Wl1p, output packed bf16, rows padded to 64 feats (128 B).
__global__ __launch_bounds__(256, 4) void gemm_y(const float* __restrict__ X,
                                                 const float* __restrict__ Wp,
                                                 unsigned int* __restrict__ Ybf)
{
    __shared__ float xs[KC * 256];   // 32 KB
    const int t  = threadIdx.x;
    const int n0 = blockIdx.x * 256;
    const int ng = t >> 3;           // 0..31
    const int fg = t & 7;            // 0..7
    const int nbase = n0 + ng * 8;

    float acc[8][8];
#pragma unroll
    for (int i = 0; i < 8; ++i)
#pragma unroll
        for (int j = 0; j < 8; ++j) acc[i][j] = 0.f;

    for (int c = 0; c < DD / KC; ++c) {
        if (c) __syncthreads();
#pragma unroll
        for (int j = 0; j < 8; ++j) {
            int f4  = j * 256 + t;
            int row = f4 >> 3;
            int c4  = f4 & 7;
            int gn  = n0 + row;
            float4 v = make_float4(0.f, 0.f, 0.f, 0.f);
            if (gn < N0V) v = *(const float4*)(X + (size_t)gn * DD + c * KC + c4 * 4);
            int kb  = c4 * 4;
            int rsw = row ^ (c4 << 3);           // swizzle by (k>>2)
            xs[(kb + 0) * 256 + rsw] = v.x;
            xs[(kb + 1) * 256 + rsw] = v.y;
            xs[(kb + 2) * 256 + rsw] = v.z;
            xs[(kb + 3) * 256 + rsw] = v.w;
        }
        __syncthreads();
#pragma unroll 4
        for (int kk = 0; kk < KC; ++kk) {
            int m = kk >> 2;
            const float* xp = &xs[kk * 256 + ((ng ^ m) << 3)];
            float4 x0 = *(const float4*)xp;
            float4 x1 = *(const float4*)(xp + 4);
            const float* wr = Wp + (size_t)(c * KC + kk) * FP + fg * 8;
            float4 w0 = *(const float4*)wr;
            float4 w1 = *(const float4*)(wr + 4);
            float xv[8] = {x0.x, x0.y, x0.z, x0.w, x1.x, x1.y, x1.z, x1.w};
            float wv[8] = {w0.x, w0.y, w0.z, w0.w, w1.x, w1.y, w1.z, w1.w};
#pragma unroll
            for (int i = 0; i < 8; ++i)
#pragma unroll
                for (int j = 0; j < 8; ++j)
                    acc[i][j] = fmaf(xv[i], wv[j], acc[i][j]);
        }
    }

    if (nbase < N0V) {   // N0 % 8 == 0 -> group fully valid
#pragma unroll
        for (int i = 0; i < 8; ++i) {
            uint4 q;
            q.x = (unsigned)f2bf(acc[i][0]) | ((unsigned)f2bf(acc[i][1]) << 16);
            q.y = (unsigned)f2bf(acc[i][2]) | ((unsigned)f2bf(acc[i][3]) << 16);
            q.z = (unsigned)f2bf(acc[i][4]) | ((unsigned)f2bf(acc[i][5]) << 16);
            q.w = (unsigned)f2bf(acc[i][6]) | ((unsigned)f2bf(acc[i][7]) << 16);
            *(uint4*)(Ybf + (size_t)(nbase + i) * 32 + fg * 4) = q;
        }
    }
}

// K2a: degree histogram of dst0
__global__ __launch_bounds__(256) void hist1(const int* __restrict__ dst,
                                             int* __restrict__ deg)
{
    int e = blockIdx.x * 256 + threadIdx.x;
    if (e < E0V) atomicAdd(&deg[dst[e]], 1);
}

// K2b: per-block inclusive scan of deg -> incl (in rowptr), block totals -> bsum
__global__ __launch_bounds__(256) void scan_a(const int* __restrict__ deg,
                                              int* __restrict__ incl,
                                              int* __restrict__ bsum)
{
    __shared__ int s[256];
    int tid = threadIdx.x;
    int i = blockIdx.x * 256 + tid;
    int v = (i < N1V) ? deg[i] : 0;
    s[tid] = v;
    __syncthreads();
#pragma unroll
    for (int off = 1; off < 256; off <<= 1) {
        int tv = (tid >= off) ? s[tid - off] : 0;
        __syncthreads();
        s[tid] += tv;
        __syncthreads();
    }
    if (i < N1V) incl[i] = s[tid];
    if (tid == 255) bsum[blockIdx.x] = s[255];
}

// K2c: exclusive scan of block sums (single block, sequential chunks)
__global__ __launch_bounds__(256) void scan_b(int* __restrict__ bsum)
{
    __shared__ int s[256];
    __shared__ int run_s;
    int tid = threadIdx.x;
    if (tid == 0) run_s = 0;
    __syncthreads();
    for (int base = 0; base < NB_SCAN; base += 256) {
        int idx = base + tid;
        int v = (idx < NB_SCAN) ? bsum[idx] : 0;
        s[tid] = v;
        __syncthreads();
#pragma unroll
        for (int off = 1; off < 256; off <<= 1) {
            int tv = (tid >= off) ? s[tid - off] : 0;
            __syncthreads();
            s[tid] += tv;
            __syncthreads();
        }
        int rbase = run_s;
        if (idx < NB_SCAN) bsum[idx] = s[tid] - v + rbase;
        __syncthreads();
        if (tid == 255) run_s = rbase + s[255];
        __syncthreads();
    }
}

// K2d: rowptr[i] = incl[i] - deg[i] + bsum[block]  (exclusive); cursor = copy
__global__ __launch_bounds__(256) void scan_c(const int* __restrict__ deg,
                                              int* __restrict__ rowptr,
                                              int* __restrict__ cursor,
                                              const int* __restrict__ bsum)
{
    int i = blockIdx.x * 256 + threadIdx.x;
    if (i < N1V) {
        int ex = rowptr[i] - deg[i] + bsum[blockIdx.x];
        rowptr[i] = ex;
        cursor[i] = ex;
    }
}

// K2e: fill CSR: csr[atomic cursor[dst]] = src
__global__ __launch_bounds__(256) void fill1(const int* __restrict__ src,
                                             const int* __restrict__ dst,
                                             int* __restrict__ cursor,
                                             int* __restrict__ csr)
{
    int e = blockIdx.x * 256 + threadIdx.x;
    if (e < E0V) {
        int d = dst[e];
        int pos = atomicAdd(&cursor[d], 1);
        csr[pos] = src[e];
    }
}

// K3: gather-mean: agg[n][0:64] = mean over neighbors of y[src] (bf16 -> f32)
// half-wave (32 lanes) per node; lane handles 2 features (one packed uint)
__global__ __launch_bounds__(256) void gather1(const unsigned int* __restrict__ Ybf,
                                               const int* __restrict__ rowptr,
                                               const int* __restrict__ deg,
                                               const int* __restrict__ csr,
                                               float* __restrict__ agg)
{
    int node = blockIdx.x * 8 + (threadIdx.x >> 5);
    int lane = threadIdx.x & 31;
    if (node >= N1V) return;
    int start = rowptr[node];
    int dg = deg[node];
    float a0 = 0.f, a1 = 0.f;
    for (int k = 0; k < dg; ++k) {
        int sI = csr[start + k];
        unsigned v = Ybf[(size_t)sI * 32 + lane];
        a0 += __uint_as_float(v << 16);
        a1 += __uint_as_float(v & 0xFFFF0000u);
    }
    float inv = 1.0f / (float)max(dg, 1);
    *(float2*)(agg + (size_t)node * FP + lane * 2) = make_float2(a0 * inv, a1 * inv);
}

// K4: d = x[:N1] @ Wr1p (tiled GEMM), epilogue:
//   h = relu(aggmean + bl1 + d);  s = h.wA;  t = h.wB  (shfl-reduce over 8 fgs)
__global__ __launch_bounds__(256, 4) void node_l1(const float* __restrict__ X,
                                                  const float* __restrict__ Wp,
                                                  const float* __restrict__ agg,
                                                  const float* __restrict__ smalls,
                                                  float* __restrict__ sArr,
                                                  float* __restrict__ tArr)
{
    __shared__ float xs[KC * 256];
    const int t  = threadIdx.x;
    const int n0 = blockIdx.x * 256;
    const int ng = t >> 3;
    const int fg = t & 7;
    const int nbase = n0 + ng * 8;

    float acc[8][8];
#pragma unroll
    for (int i = 0; i < 8; ++i)
#pragma unroll
        for (int j = 0; j < 8; ++j) acc[i][j] = 0.f;

    for (int c = 0; c < DD / KC; ++c) {
        if (c) __syncthreads();
#pragma unroll
        for (int j = 0; j < 8; ++j) {
            int f4  = j * 256 + t;
            int row = f4 >> 3;
            int c4  = f4 & 7;
            int gn  = n0 + row;
            float4 v = make_float4(0.f, 0.f, 0.f, 0.f);
            if (gn < N1V) v = *(const float4*)(X + (size_t)gn * DD + c * KC + c4 * 4);
            int kb  = c4 * 4;
            int rsw = row ^ (c4 << 3);
            xs[(kb + 0) * 256 + rsw] = v.x;
            xs[(kb + 1) * 256 + rsw] = v.y;
            xs[(kb + 2) * 256 + rsw] = v.z;
            xs[(kb + 3) * 256 + rsw] = v.w;
        }
        __syncthreads();
#pragma unroll 4
        for (int kk = 0; kk < KC; ++kk) {
            int m = kk >> 2;
            const float* xp = &xs[kk * 256 + ((ng ^ m) << 3)];
            float4 x0 = *(const float4*)xp;
            float4 x1 = *(const float4*)(xp + 4);
            const float* wr = Wp + (size_t)(c * KC + kk) * FP + fg * 8;
            float4 w0 = *(const float4*)wr;
            float4 w1 = *(const float4*)(wr + 4);
            float xv[8] = {x0.x, x0.y, x0.z, x0.w, x1.x, x1.y, x1.z, x1.w};
            float wv[8] = {w0.x, w0.y, w0.z, w0.w, w1.x, w1.y, w1.z, w1.w};
#pragma unroll
            for (int i = 0; i < 8; ++i)
#pragma unroll
                for (int j = 0; j < 8; ++j)
                    acc[i][j] = fmaf(xv[i], wv[j], acc[i][j]);
        }
    }

    if (nbase >= N1V) return;   // no further barriers

    const float* blp = smalls + fg * 8;
    const float* wAp = smalls + FP + fg * 8;
    const float* wBp = smalls + 2 * FP + fg * 8;
    float bl_r[8], wA_r[8], wB_r[8];
#pragma unroll
    for (int j = 0; j < 8; ++j) { bl_r[j] = blp[j]; wA_r[j] = wAp[j]; wB_r[j] = wBp[j]; }

    float ps[8], pt[8];
#pragma unroll
    for (int i = 0; i < 8; ++i) {
        int n = nbase + i;
        const float* ar = agg + (size_t)n * FP + fg * 8;
        float4 a0 = *(const float4*)ar;
        float4 a1 = *(const float4*)(ar + 4);
        float agf[8] = {a0.x, a0.y, a0.z, a0.w, a1.x, a1.y, a1.z, a1.w};
        float s_acc = 0.f, t_acc = 0.f;
#pragma unroll
        for (int j = 0; j < 8; ++j) {
            float h = fmaxf(agf[j] + bl_r[j] + acc[i][j], 0.f);
            s_acc = fmaf(h, wA_r[j], s_acc);
            t_acc = fmaf(h, wB_r[j], t_acc);
        }
        ps[i] = s_acc; pt[i] = t_acc;
    }
#pragma unroll
    for (int i = 0; i < 8; ++i) {
#pragma unroll
        for (int m = 1; m < 8; m <<= 1) {
            ps[i] += __shfl_xor(ps[i], m);
            pt[i] += __shfl_xor(pt[i], m);
        }
    }
    if (fg == 0) {
#pragma unroll
        for (int i = 0; i < 8; ++i) sArr[nbase + i] = ps[i];
        if (nbase < N2V) {
#pragma unroll
            for (int i = 0; i < 8; ++i) tArr[nbase + i] = pt[i];
        }
    }
}

// K5: edge scatter layer 2 (scalar atomics; only 500k edges)
__global__ __launch_bounds__(256) void scatter2(const float* __restrict__ sArr,
                                                const int* __restrict__ src,
                                                const int* __restrict__ dst,
                                                float* __restrict__ ssum,
                                                float* __restrict__ cnt2)
{
    int e = blockIdx.x * 256 + threadIdx.x;
    if (e >= E1V) return;
    int sI = src[e];
    int dI = dst[e];
    atomicAdd(&ssum[dI], sArr[sI]);
    atomicAdd(&cnt2[dI], 1.0f);
}

// K6: out[i] = relu(ssum[i]/max(cnt2,1) + t[i] + c)
__global__ __launch_bounds__(256) void final_out(const float* __restrict__ ssum,
                                                 const float* __restrict__ cnt2,
                                                 const float* __restrict__ tArr,
                                                 const float* __restrict__ smalls,
                                                 float* __restrict__ out)
{
    int i = blockIdx.x * 256 + threadIdx.x;
    if (i >= N2V) return;
    float c = smalls[3 * FP];
    float inv = 1.0f / fmaxf(cnt2[i], 1.0f);
    float o = fmaf(ssum[i], inv, tArr[i] + c);
    out[i] = fmaxf(o, 0.f);
}

extern "C" void kernel_launch(void* const* d_in, const int* in_sizes, int n_in,
                              void* d_out, int out_size, void* d_ws, size_t ws_size,
                              hipStream_t stream)
{
    if (ws_size < WS_NEEDED) return;

    const float* x    = (const float*)d_in[0];
    const int*   src0 = (const int*)d_in[2];
    const int*   dst0 = (const int*)d_in[3];
    const int*   src1 = (const int*)d_in[4];
    const int*   dst1 = (const int*)d_in[5];
    const float* Wl1  = (const float*)d_in[8];
    const float* bl1  = (const float*)d_in[9];
    const float* Wr1  = (const float*)d_in[10];
    const float* Wl2  = (const float*)d_in[11];
    const float* bl2  = (const float*)d_in[12];
    const float* Wr2  = (const float*)d_in[13];
    const float* Wo   = (const float*)d_in[14];
    const float* bo   = (const float*)d_in[15];
    float* out = (float*)d_out;

    char* ws = (char*)d_ws;
    int*   deg    = (int*)(ws + OFF_DEG);
    float* ssum   = (float*)(ws + OFF_SSUM);
    float* cnt2   = (float*)(ws + OFF_CNT2);
    int*   rowptr = (int*)(ws + OFF_ROWPTR);
    int*   cursor = (int*)(ws + OFF_CURSOR);
    int*   bsum   = (int*)(ws + OFF_BSUM);
    float* smalls = (float*)(ws + OFF_SMALL);
    float* Wl1p   = (float*)(ws + OFF_WL1P);
    float* Wr1p   = (float*)(ws + OFF_WR1P);
    float* sArr   = (float*)(ws + OFF_S);
    float* tArr   = (float*)(ws + OFF_T);
    int*   csr    = (int*)(ws + OFF_CSR);
    float* agg    = (float*)(ws + OFF_AGG);
    unsigned int* ybf = (unsigned int*)(ws + OFF_Y);

    hipMemsetAsync(d_ws, 0, ZERO_BYTES, stream);

    pad_w<<<32, 256, 0, stream>>>(Wl1, Wr1, bl1, Wl2, bl2, Wr2, Wo, bo, Wl1p, Wr1p, smalls);

    gemm_y<<<(N0V + 255) / 256, 256, 0, stream>>>(x, Wl1p, ybf);

    // CSR build for layer-1 edges
    hist1<<<(E0V + 255) / 256, 256, 0, stream>>>(dst0, deg);
    scan_a<<<NB_SCAN, 256, 0, stream>>>(deg, rowptr, bsum);
    scan_b<<<1, 256, 0, stream>>>(bsum);
    scan_c<<<NB_SCAN, 256, 0, stream>>>(deg, rowptr, cursor, bsum);
    fill1<<<(E0V + 255) / 256, 256, 0, stream>>>(src0, dst0, cursor, csr);

    gather1<<<(N1V + 7) / 8, 256, 0, stream>>>(ybf, rowptr, deg, csr, agg);

    node_l1<<<NB_SCAN, 256, 0, stream>>>(x, Wr1p, agg, smalls, sArr, tArr);

    scatter2<<<(E1V + 255) / 256, 256, 0, stream>>>(sArr, src1, dst1, ssum, cnt2);

    final_out<<<(N2V + 255) / 256, 256, 0, stream>>>(ssum, cnt2, tArr, smalls, out);
}